// Round 1
// 1090.335 us; speedup vs baseline: 1.2202x; 1.2202x over previous
//
#include <hip/hip_runtime.h>

typedef __bf16 bf16;
typedef __bf16 bf16x8 __attribute__((ext_vector_type(8)));
typedef float floatx16 __attribute__((ext_vector_type(16)));

#define DEV static __device__ __forceinline__
#define SCALE 0.07216878364870323f  /* (128+64)^-0.5 */

union U8 { bf16x8 v; uint2 u[2]; };

DEV unsigned pk2(float x, float y) {
  union { __bf16 h[2]; unsigned u; } r;
  r.h[0] = (__bf16)x; r.h[1] = (__bf16)y;
  return r.u;
}

// ---------------- K1: q_a_raw = h @ Wq_a ; kv_raw = h @ Wkv_a (split-K atomics)
// grid (9, 40): 128-k chunks -> 360 blocks (was 180) for latency hiding
__global__ __launch_bounds__(256) void k1_gemm_qa_kv(
    const float* __restrict__ h, const float* __restrict__ Wq_a,
    const float* __restrict__ Wkv_a, float* __restrict__ q_a_raw,
    float* __restrict__ kv_raw)
{
  const int cb = blockIdx.x;      // 0..8   (256 cols each, 2112 total)
  const int kc = blockIdx.y;      // 0..39  (128 k each, 5120 total)
  const int t  = threadIdx.x;
  const int j  = cb*256 + t;
  const int kbase = kc*128;
  __shared__ __align__(16) float hs[32][128];
  {
    int b2 = t >> 3, k0 = (t & 7)*16;
    const float4* src = (const float4*)(h + (size_t)b2*5120 + kbase + k0);
    float4* dst = (float4*)&hs[b2][k0];
#pragma unroll
    for (int i = 0; i < 4; i++) dst[i] = src[i];
  }
  __syncthreads();
  float acc[32];
#pragma unroll
  for (int b2 = 0; b2 < 32; b2++) acc[b2] = 0.f;
  if (j < 2112) {
    const float* W; int ldw, jj;
    if (j < 1536) { W = Wq_a;  ldw = 1536; jj = j; }
    else          { W = Wkv_a; ldw = 576;  jj = j - 1536; }
    for (int k = 0; k < 128; k += 4) {
      float w0 = W[(size_t)(kbase+k+0)*ldw + jj];
      float w1 = W[(size_t)(kbase+k+1)*ldw + jj];
      float w2 = W[(size_t)(kbase+k+2)*ldw + jj];
      float w3 = W[(size_t)(kbase+k+3)*ldw + jj];
#pragma unroll
      for (int b2 = 0; b2 < 32; b2++) {
        float4 q = *(const float4*)&hs[b2][k];
        acc[b2] += q.x*w0 + q.y*w1 + q.z*w2 + q.w*w3;
      }
    }
    if (j < 1536) {
#pragma unroll
      for (int b2 = 0; b2 < 32; b2++) atomicAdd(&q_a_raw[b2*1536 + j], acc[b2]);
    } else {
#pragma unroll
      for (int b2 = 0; b2 < 32; b2++) atomicAdd(&kv_raw[b2*576 + (j-1536)], acc[b2]);
    }
  }
}

// ---------------- K2: rmsnorms + rope(k_pe) + cache scatter
__global__ __launch_bounds__(256) void k2_norms(
    const float* __restrict__ q_a_raw, const float* __restrict__ kv_raw,
    const float* __restrict__ q_ln_w, const float* __restrict__ kv_ln_w,
    const float* __restrict__ cosp, const float* __restrict__ sinp,
    const int* __restrict__ slot_mapping,
    float* __restrict__ q_a_ln, float* __restrict__ cache_kv,
    float* __restrict__ cache_pe)
{
  const int b = blockIdx.x, t = threadIdx.x;
  __shared__ float red[256];
  float v[6]; float ss = 0.f;
#pragma unroll
  for (int i = 0; i < 6; i++) { v[i] = q_a_raw[b*1536 + i*256 + t]; ss += v[i]*v[i]; }
  red[t] = ss; __syncthreads();
  for (int s = 128; s > 0; s >>= 1) { if (t < s) red[t] += red[t+s]; __syncthreads(); }
  float sq = rsqrtf(red[0]/1536.f + 1e-6f);
#pragma unroll
  for (int i = 0; i < 6; i++) q_a_ln[b*1536 + i*256 + t] = v[i]*sq*q_ln_w[i*256 + t];
  __syncthreads();
  float u0 = kv_raw[b*576 + t], u1 = kv_raw[b*576 + 256 + t];
  red[t] = u0*u0 + u1*u1; __syncthreads();
  for (int s = 128; s > 0; s >>= 1) { if (t < s) red[t] += red[t+s]; __syncthreads(); }
  float skv = rsqrtf(red[0]/512.f + 1e-6f);
  const int slot = slot_mapping[b];
  cache_kv[(size_t)slot*512 + t]       = u0*skv*kv_ln_w[t];
  cache_kv[(size_t)slot*512 + 256 + t] = u1*skv*kv_ln_w[256 + t];
  if (t < 32) {
    float x1 = kv_raw[b*576 + 512 + 2*t], x2 = kv_raw[b*576 + 512 + 2*t + 1];
    float c = cosp[b*32 + t], s = sinp[b*32 + t];
    cache_pe[(size_t)slot*64 + 2*t]     = x1*c - x2*s;
    cache_pe[(size_t)slot*64 + 2*t + 1] = x2*c + x1*s;
  }
}

// ---------------- K3: q = q_a_ln @ Wq_b  -> q_nope / q_pe_raw (split-K atomics)
// grid (96, 6): 256-k chunks -> 576 blocks (was 288)
__global__ __launch_bounds__(256) void k3_gemm_qb(
    const float* __restrict__ q_a_ln, const float* __restrict__ Wq_b,
    float* __restrict__ q_nope, float* __restrict__ q_pe_raw)
{
  const int cb = blockIdx.x, kc = blockIdx.y, t = threadIdx.x;
  const int j = cb*256 + t;  // 0..24575
  const int kbase = kc*256;
  __shared__ __align__(16) float hs[32][256];
  float acc[32];
#pragma unroll
  for (int b2 = 0; b2 < 32; b2++) acc[b2] = 0.f;
  {
    int b2 = t >> 3, k0 = (t & 7)*32;
    const float4* src = (const float4*)(q_a_ln + b2*1536 + kbase + k0);
    float4* dst = (float4*)&hs[b2][k0];
#pragma unroll
    for (int i = 0; i < 8; i++) dst[i] = src[i];
  }
  __syncthreads();
  for (int k = 0; k < 256; k += 4) {
    float w0 = Wq_b[(size_t)(kbase+k+0)*24576 + j];
    float w1 = Wq_b[(size_t)(kbase+k+1)*24576 + j];
    float w2 = Wq_b[(size_t)(kbase+k+2)*24576 + j];
    float w3 = Wq_b[(size_t)(kbase+k+3)*24576 + j];
#pragma unroll
    for (int b2 = 0; b2 < 32; b2++) {
      float4 q = *(const float4*)&hs[b2][k];
      acc[b2] += q.x*w0 + q.y*w1 + q.z*w2 + q.w*w3;
    }
  }
  const int h = j/192, r = j - h*192;
  if (r < 128) {
#pragma unroll
    for (int b2 = 0; b2 < 32; b2++) atomicAdd(&q_nope[(size_t)(b2*128+h)*128 + r], acc[b2]);
  } else {
#pragma unroll
    for (int b2 = 0; b2 < 32; b2++) atomicAdd(&q_pe_raw[(size_t)(b2*128+h)*64 + (r-128)], acc[b2]);
  }
}

// ---------------- K4: rope(q_pe) * scale -> bf16 q_full[...,512:576]
__global__ __launch_bounds__(256) void k4_ropeq(
    const float* __restrict__ q_pe_raw, const float* __restrict__ cosp,
    const float* __restrict__ sinp, bf16* __restrict__ q_full)
{
  int idx = blockIdx.x*256 + threadIdx.x;  // 32*128*32 pairs
  int i = idx & 31, row = idx >> 5, b = row >> 7;
  float2 x = *(const float2*)(q_pe_raw + (size_t)row*64 + 2*i);
  float c = cosp[b*32 + i], s = sinp[b*32 + i];
  float o1 = (x.x*c - x.y*s)*SCALE;
  float o2 = (x.y*c + x.x*s)*SCALE;
  *(unsigned*)(q_full + (size_t)row*576 + 512 + 2*i) = pk2(o1, o2);
}

// ---------------- K5: q_lat[b,h,k] = sum_d q_nope * W_UK_T, * scale -> bf16 q_full[...,0:512]
__global__ __launch_bounds__(256) void k5_qlat(
    const float* __restrict__ q_nope, const float* __restrict__ W_UK_T,
    bf16* __restrict__ q_full)
{
  const int hh = blockIdx.x, cbk = blockIdx.y, t = threadIdx.x;
  const int k = cbk*256 + t;
  __shared__ __align__(16) float qs[32][128];
  {
    int b2 = t >> 3, d0 = (t & 7)*16;
    const float4* src = (const float4*)(q_nope + (size_t)(b2*128+hh)*128 + d0);
    float4* dst = (float4*)&qs[b2][d0];
#pragma unroll
    for (int i = 0; i < 4; i++) dst[i] = src[i];
  }
  __syncthreads();
  float acc[32];
#pragma unroll
  for (int b2 = 0; b2 < 32; b2++) acc[b2] = 0.f;
  const float* W = W_UK_T + (size_t)hh*65536 + k;
  for (int d = 0; d < 128; d += 4) {
    float w0 = W[(d+0)*512], w1 = W[(d+1)*512], w2 = W[(d+2)*512], w3 = W[(d+3)*512];
#pragma unroll
    for (int b2 = 0; b2 < 32; b2++) {
      float4 q = *(const float4*)&qs[b2][d];
      acc[b2] += q.x*w0 + q.y*w1 + q.z*w2 + q.w*w3;
    }
  }
#pragma unroll
  for (int b2 = 0; b2 < 32; b2++)
    q_full[(size_t)(b2*128+hh)*576 + k] = (bf16)(acc[b2]*SCALE);
}

// ---------------- K6: flash-decode attention, bf16 MFMA 32x32x16
__global__ __launch_bounds__(256, 1) void k6_attn(
    const float* __restrict__ cache_kv, const float* __restrict__ cache_pe,
    const int* __restrict__ block_table, const bf16* __restrict__ q_full,
    float* __restrict__ part_ctx, float* __restrict__ part_m,
    float* __restrict__ part_l)
{
  const int b = blockIdx.x;      // batch
  const int hg = blockIdx.y;     // head group (32 heads)
  const int chunk = blockIdx.z;  // S chunk (1024 pos)
  const int t = threadIdx.x;
  const int w = t >> 6, l = t & 63, l31 = l & 31, lh = l >> 5;

  __shared__ __align__(16) bf16 kS[32][580];   // [pos][feat 0..575]
  __shared__ __align__(16) bf16 kT[512][36];   // [feat][pos]
  __shared__ __align__(16) float s_red[4][32][33];
  __shared__ __align__(16) bf16 P_s[32][36];   // [head][pos]
  __shared__ __align__(16) float alpha_s[32];

  // q A-fragments in registers: wave w owns feats [w*144, w*144+144)
  bf16x8 qf[9];
  {
    const bf16* qp = q_full + (size_t)(b*128 + hg*32 + l31)*576 + w*144 + lh*8;
#pragma unroll
    for (int kk = 0; kk < 9; kk++) qf[kk] = *(const bf16x8*)(qp + kk*16);
  }
  floatx16 acc[4];
#pragma unroll
  for (int nt = 0; nt < 4; nt++)
#pragma unroll
    for (int r = 0; r < 16; r++) acc[nt][r] = 0.f;
  float m_run = -3.0e38f, l_run = 0.f;

  const int pos0 = (t & 3)*8, feat0 = (t >> 2)*8;
  const int ppos = t >> 3, pf0 = (t & 7)*8;

  for (int tile = 0; tile < 32; tile++) {
    const int pg = chunk*1024 + tile*32;
    const int cblk = block_table[b*16 + (pg >> 7)];
    const float* kvp = cache_kv + ((size_t)cblk*128 + (pg & 127))*512;
    const float* pep = cache_pe + ((size_t)cblk*128 + (pg & 127))*64;

    // global loads (issued before barrier for overlap)
    float va[8][8];
    {
      const float* p0 = kvp + (size_t)pos0*512 + feat0;
#pragma unroll
      for (int i = 0; i < 8; i++) {
        float4 x = *(const float4*)(p0 + i*512);
        float4 y = *(const float4*)(p0 + i*512 + 4);
        va[i][0]=x.x; va[i][1]=x.y; va[i][2]=x.z; va[i][3]=x.w;
        va[i][4]=y.x; va[i][5]=y.y; va[i][6]=y.z; va[i][7]=y.w;
      }
    }
    float pv[8];
    {
      const float* pp = pep + (size_t)ppos*64 + pf0;
      float4 x = *(const float4*)pp; float4 y = *(const float4*)(pp + 4);
      pv[0]=x.x; pv[1]=x.y; pv[2]=x.z; pv[3]=x.w;
      pv[4]=y.x; pv[5]=y.y; pv[6]=y.z; pv[7]=y.w;
    }

    __syncthreads();  // prev tile's MFMA reads of kS/kT/P_s done

    // stage kS rows + kT transposed cols + pe
#pragma unroll
    for (int i = 0; i < 8; i++) {
      uint2 w0, w1;
      w0.x = pk2(va[i][0], va[i][1]); w0.y = pk2(va[i][2], va[i][3]);
      w1.x = pk2(va[i][4], va[i][5]); w1.y = pk2(va[i][6], va[i][7]);
      *(uint2*)&kS[pos0+i][feat0]   = w0;
      *(uint2*)&kS[pos0+i][feat0+4] = w1;
    }
#pragma unroll
    for (int jj = 0; jj < 8; jj++) {
      uint2 w0, w1;
      w0.x = pk2(va[0][jj], va[1][jj]); w0.y = pk2(va[2][jj], va[3][jj]);
      w1.x = pk2(va[4][jj], va[5][jj]); w1.y = pk2(va[6][jj], va[7][jj]);
      *(uint2*)&kT[feat0+jj][pos0]   = w0;
      *(uint2*)&kT[feat0+jj][pos0+4] = w1;
    }
    {
      uint2 w0, w1;
      w0.x = pk2(pv[0], pv[1]); w0.y = pk2(pv[2], pv[3]);
      w1.x = pk2(pv[4], pv[5]); w1.y = pk2(pv[6], pv[7]);
      *(uint2*)&kS[ppos][512+pf0]   = w0;
      *(uint2*)&kS[ppos][512+pf0+4] = w1;
    }
    __syncthreads();

    // scores: partial over this wave's K range (9 k-steps of 16)
    floatx16 sc;
#pragma unroll
    for (int r = 0; r < 16; r++) sc[r] = 0.f;
#pragma unroll
    for (int kk = 0; kk < 9; kk++) {
      U8 bfg;
      const bf16* bp = &kS[l31][w*144 + kk*16 + lh*8];
      bfg.u[0] = *(const uint2*)bp; bfg.u[1] = *(const uint2*)(bp + 4);
      sc = __builtin_amdgcn_mfma_f32_32x32x16_bf16(qf[kk], bfg.v, sc, 0, 0, 0);
    }
#pragma unroll
    for (int r = 0; r < 16; r++) {
      int row = (r & 3) + 8*(r >> 2) + 4*lh;
      s_red[w][row][l31] = sc[r];
    }
    __syncthreads();

    // phase A: cross-wave reduce into s_red[0]
    {
      int h = t >> 3, p0 = (t & 7)*4;
#pragma unroll
      for (int i = 0; i < 4; i++) {
        int p = p0 + i;
        s_red[0][h][p] = s_red[0][h][p] + s_red[1][h][p] + s_red[2][h][p] + s_red[3][h][p];
      }
    }
    __syncthreads();

    // phase B: online softmax (each wave redundantly; per-lane head = l31)
    {
      const int h = l31;
      float sb[32];
      float tmax = -3.0e38f;
#pragma unroll
      for (int p = 0; p < 32; p++) { sb[p] = s_red[0][h][p]; tmax = fmaxf(tmax, sb[p]); }
      float m_new = fmaxf(m_run, tmax);
      float alpha = __expf(m_run - m_new);
      float lsum = 0.f;
#pragma unroll
      for (int p = 0; p < 32; p++) { sb[p] = __expf(sb[p] - m_new); lsum += sb[p]; }
      l_run = l_run*alpha + lsum;
      m_run = m_new;
      if (l < 32) {
#pragma unroll
        for (int p0b = 0; p0b < 32; p0b += 8) {
          if (p0b == w*8) {
            uint2 lo, hi;
            lo.x = pk2(sb[p0b+0], sb[p0b+1]); lo.y = pk2(sb[p0b+2], sb[p0b+3]);
            hi.x = pk2(sb[p0b+4], sb[p0b+5]); hi.y = pk2(sb[p0b+6], sb[p0b+7]);
            *(uint2*)&P_s[h][p0b]   = lo;
            *(uint2*)&P_s[h][p0b+4] = hi;
          }
        }
        if (w == 0) alpha_s[h] = alpha;
      }
    }
    __syncthreads();

    // rescale acc + ctx MFMA (wave w owns feats [w*128, w*128+128))
    {
      float4 a0 = *(const float4*)&alpha_s[4*lh];
      float4 a1 = *(const float4*)&alpha_s[8 + 4*lh];
      float4 a2 = *(const float4*)&alpha_s[16 + 4*lh];
      float4 a3 = *(const float4*)&alpha_s[24 + 4*lh];
      float alv[16] = {a0.x,a0.y,a0.z,a0.w, a1.x,a1.y,a1.z,a1.w,
                       a2.x,a2.y,a2.z,a2.w, a3.x,a3.y,a3.z,a3.w};
#pragma unroll
      for (int nt = 0; nt < 4; nt++)
#pragma unroll
        for (int r = 0; r < 16; r++) acc[nt][r] *= alv[r];
    }
#pragma unroll
    for (int ks = 0; ks < 2; ks++) {
      U8 af;
      const bf16* ap = &P_s[l31][ks*16 + lh*8];
      af.u[0] = *(const uint2*)ap; af.u[1] = *(const uint2*)(ap + 4);
#pragma unroll
      for (int nt = 0; nt < 4; nt++) {
        U8 bfg;
        const bf16* bp2 = &kT[w*128 + nt*32 + l31][ks*16 + lh*8];
        bfg.u[0] = *(const uint2*)bp2; bfg.u[1] = *(const uint2*)(bp2 + 4);
        acc[nt] = __builtin_amdgcn_mfma_f32_32x32x16_bf16(af.v, bfg.v, acc[nt], 0, 0, 0);
      }
    }
  }

  // epilogue: unnormalized partials + m/l
  const size_t obase = (size_t)(b*2 + chunk)*128 + hg*32;
#pragma unroll
  for (int nt = 0; nt < 4; nt++) {
    int feat = w*128 + nt*32 + l31;
#pragma unroll
    for (int r = 0; r < 16; r++) {
      int row = (r & 3) + 8*(r >> 2) + 4*lh;
      part_ctx[(obase + row)*512 + feat] = acc[nt][r];
    }
  }
  if (t < 32) {
    int o = (b*2 + chunk)*128 + hg*32 + t;
    part_m[o] = m_run;
    part_l[o] = l_run;
  }
}

// ---------------- K7: combine flash partials + out_uv = ctx @ W_UV[h]
__global__ __launch_bounds__(256) void k7_combine_uv(
    const float* __restrict__ part_ctx, const float* __restrict__ part_m,
    const float* __restrict__ part_l, const float* __restrict__ W_UV,
    float* __restrict__ out_uv)
{
  const int hh = blockIdx.x, vh = blockIdx.y, t = threadIdx.x;
  __shared__ __align__(16) float ctx_s[32][512];
  {
    int bb = t >> 3;
    float m0 = part_m[(bb*2+0)*128 + hh], m1 = part_m[(bb*2+1)*128 + hh];
    float l0 = part_l[(bb*2+0)*128 + hh], l1 = part_l[(bb*2+1)*128 + hh];
    float M = fmaxf(m0, m1);
    float e0 = __expf(m0 - M), e1 = __expf(m1 - M);
    float Li = 1.f/(e0*l0 + e1*l1);
    float w0 = e0*Li, w1 = e1*Li;
    int k0 = (t & 7)*64;
    const float* p0 = part_ctx + ((size_t)(bb*2+0)*128 + hh)*512 + k0;
    const float* p1 = part_ctx + ((size_t)(bb*2+1)*128 + hh)*512 + k0;
#pragma unroll
    for (int i = 0; i < 64; i += 4) {
      float4 x = *(const float4*)(p0 + i);
      float4 y = *(const float4*)(p1 + i);
      float4 z; z.x = w0*x.x + w1*y.x; z.y = w0*x.y + w1*y.y;
      z.z = w0*x.z + w1*y.z; z.w = w0*x.w + w1*y.w;
      *(float4*)&ctx_s[bb][k0 + i] = z;
    }
  }
  __syncthreads();
  const int v = vh*64 + (t & 63);
  const int kq = t >> 6;
  float acc[32];
#pragma unroll
  for (int b2 = 0; b2 < 32; b2++) acc[b2] = 0.f;
  const float* W = W_UV + (size_t)hh*512*128 + v;
  for (int k = kq*128; k < kq*128 + 128; k += 4) {
    float w0 = W[(k+0)*128], w1 = W[(k+1)*128], w2 = W[(k+2)*128], w3 = W[(k+3)*128];
#pragma unroll
    for (int b2 = 0; b2 < 32; b2++) {
      float4 q = *(const float4*)&ctx_s[b2][k];
      acc[b2] += q.x*w0 + q.y*w1 + q.z*w2 + q.w*w3;
    }
  }
  __syncthreads();
  float* partial = &ctx_s[0][0];  // reuse (8192 floats needed)
#pragma unroll
  for (int b2 = 0; b2 < 32; b2++) partial[((size_t)kq*32 + b2)*64 + (t & 63)] = acc[b2];
  __syncthreads();
#pragma unroll
  for (int i = 0; i < 8; i++) {
    int e = i*256 + t;
    int bb = e >> 6, vv = e & 63;
    float s = partial[(0*32+bb)*64 + vv] + partial[(1*32+bb)*64 + vv]
            + partial[(2*32+bb)*64 + vv] + partial[(3*32+bb)*64 + vv];
    out_uv[(size_t)bb*16384 + hh*128 + vh*64 + vv] = s;
  }
}

// ---------------- K8: out = out_uv @ Wo (split-K atomics)
// grid (20, 32): 512-k chunks (2 subs of 256) -> 640 blocks (was 320)
__global__ __launch_bounds__(256) void k8_out(
    const float* __restrict__ out_uv, const float* __restrict__ Wo,
    float* __restrict__ outp)
{
  const int cb = blockIdx.x, kc = blockIdx.y, t = threadIdx.x;
  const int j = cb*256 + t;
  __shared__ __align__(16) float hs[32][256];
  float acc[32];
#pragma unroll
  for (int b2 = 0; b2 < 32; b2++) acc[b2] = 0.f;
  for (int sub = 0; sub < 2; sub++) {
    const int kbase = kc*512 + sub*256;
    __syncthreads();
    {
      int b2 = t >> 3, k0 = (t & 7)*32;
      const float4* src = (const float4*)(out_uv + (size_t)b2*16384 + kbase + k0);
      float4* dst = (float4*)&hs[b2][k0];
#pragma unroll
      for (int i = 0; i < 8; i++) dst[i] = src[i];
    }
    __syncthreads();
    for (int k = 0; k < 256; k += 4) {
      float w0 = Wo[(size_t)(kbase+k+0)*5120 + j];
      float w1 = Wo[(size_t)(kbase+k+1)*5120 + j];
      float w2 = Wo[(size_t)(kbase+k+2)*5120 + j];
      float w3 = Wo[(size_t)(kbase+k+3)*5120 + j];
#pragma unroll
      for (int b2 = 0; b2 < 32; b2++) {
        float4 q = *(const float4*)&hs[b2][k];
        acc[b2] += q.x*w0 + q.y*w1 + q.z*w2 + q.w*w3;
      }
    }
  }
#pragma unroll
  for (int b2 = 0; b2 < 32; b2++) atomicAdd(&outp[b2*5120 + j], acc[b2]);
}

extern "C" void kernel_launch(void* const* d_in, const int* in_sizes, int n_in,
                              void* d_out, int out_size, void* d_ws, size_t ws_size,
                              hipStream_t stream) {
  const float* h       = (const float*)d_in[0];
  const float* cosp    = (const float*)d_in[1];
  const float* sinp    = (const float*)d_in[2];
  const float* Wq_a    = (const float*)d_in[3];
  const float* q_ln_w  = (const float*)d_in[4];
  const float* Wq_b    = (const float*)d_in[5];
  const float* Wkv_a   = (const float*)d_in[6];
  const float* kv_ln_w = (const float*)d_in[7];
  const float* W_UK_T  = (const float*)d_in[8];
  const float* W_UV    = (const float*)d_in[9];
  const float* Wo      = (const float*)d_in[10];
  float* cache_kv      = (float*)d_in[11];  // updated in-place (harness restores)
  float* cache_pe      = (float*)d_in[12];
  const int* block_table  = (const int*)d_in[13];
  const int* slot_mapping = (const int*)d_in[14];
  float* outp = (float*)d_out;

  char* ws = (char*)d_ws;
  float* q_a_raw  = (float*)(ws + 0);
  float* kv_raw   = (float*)(ws + 196608);
  float* q_nope   = (float*)(ws + 270336);
  float* q_pe_raw = (float*)(ws + 2367488);
  float* q_a_ln   = (float*)(ws + 3416064);
  bf16*  q_full   = (bf16*) (ws + 3612672);
  float* part_ctx = (float*)(ws + 8331264);
  float* part_m   = (float*)(ws + 25108480);
  float* part_l   = (float*)(ws + 25141248);
  float* out_uv   = (float*)(ws + 25174016);

  hipMemsetAsync(ws, 0, 3416064, stream);          // atomic targets: q_a_raw, kv_raw, q_nope, q_pe_raw
  hipMemsetAsync(outp, 0, (size_t)32*5120*4, stream);

  k1_gemm_qa_kv<<<dim3(9, 40), 256, 0, stream>>>(h, Wq_a, Wkv_a, q_a_raw, kv_raw);
  k2_norms<<<32, 256, 0, stream>>>(q_a_raw, kv_raw, q_ln_w, kv_ln_w, cosp, sinp,
                                   slot_mapping, q_a_ln, cache_kv, cache_pe);
  k3_gemm_qb<<<dim3(96, 6), 256, 0, stream>>>(q_a_ln, Wq_b, q_nope, q_pe_raw);
  k4_ropeq<<<512, 256, 0, stream>>>(q_pe_raw, cosp, sinp, q_full);
  k5_qlat<<<dim3(128, 2), 256, 0, stream>>>(q_nope, W_UK_T, q_full);
  k6_attn<<<dim3(32, 4, 2), 256, 0, stream>>>(cache_kv, cache_pe, block_table, q_full,
                                              part_ctx, part_m, part_l);
  k7_combine_uv<<<dim3(128, 2), 256, 0, stream>>>(part_ctx, part_m, part_l, W_UV, out_uv);
  k8_out<<<dim3(20, 32), 256, 0, stream>>>(out_uv, Wo, outp);
}